// Round 2
// baseline (228.389 us; speedup 1.0000x reference)
//
#include <hip/hip_runtime.h>
#include <math.h>

#define NEARP 0.01f
#define BLUR 0.3f
#define MAX_ALPHA 0.999f
#define TILE 16
#define CHUNK 256
#define MAXN 4096

__device__ __forceinline__ float sigmoidf_(float x) {
    return 1.0f / (1.0f + expf(-x));
}

// ---------------------------------------------------------------------------
// Stage 1: per-(camera,gaussian) preprocess -> 3x float4 struct + tz
// struct layout: f0=(mean2d.x, mean2d.y, ia, ib)  f1=(ic, opac, r, g)  f2=(b,-,-,-)
// ---------------------------------------------------------------------------
__global__ void gs_preprocess(const float* __restrict__ viewmats,
                              const float* __restrict__ Ks,
                              const float* __restrict__ means,
                              const float* __restrict__ quats,
                              const float* __restrict__ log_scales,
                              const float* __restrict__ opac_logits,
                              const float* __restrict__ color_logits,
                              float4* __restrict__ unsorted,  // C*N*3 float4
                              float* __restrict__ tz_out,     // C*N
                              int N, int C) {
    int idx = blockIdx.x * blockDim.x + threadIdx.x;
    if (idx >= N * C) return;
    int c = idx / N;
    int n = idx - c * N;

    // quaternion -> R (normalized)
    float qw = quats[n * 4 + 0], qx = quats[n * 4 + 1];
    float qy = quats[n * 4 + 2], qz = quats[n * 4 + 3];
    float qn = rsqrtf(qw * qw + qx * qx + qy * qy + qz * qz);
    float w = qw * qn, x = qx * qn, y = qy * qn, z = qz * qn;
    float R00 = 1.0f - 2.0f * (y * y + z * z), R01 = 2.0f * (x * y - w * z), R02 = 2.0f * (x * z + w * y);
    float R10 = 2.0f * (x * y + w * z), R11 = 1.0f - 2.0f * (x * x + z * z), R12 = 2.0f * (y * z - w * x);
    float R20 = 2.0f * (x * z - w * y), R21 = 2.0f * (y * z + w * x), R22 = 1.0f - 2.0f * (x * x + y * y);

    float s0 = expf(log_scales[n * 3 + 0]);
    float s1 = expf(log_scales[n * 3 + 1]);
    float s2 = expf(log_scales[n * 3 + 2]);

    // M = R * diag(s)  (scale columns), cov3d = M M^T
    float M00 = R00 * s0, M01 = R01 * s1, M02 = R02 * s2;
    float M10 = R10 * s0, M11 = R11 * s1, M12 = R12 * s2;
    float M20 = R20 * s0, M21 = R21 * s1, M22 = R22 * s2;
    float C00 = M00 * M00 + M01 * M01 + M02 * M02;
    float C01 = M00 * M10 + M01 * M11 + M02 * M12;
    float C02 = M00 * M20 + M01 * M21 + M02 * M22;
    float C11 = M10 * M10 + M11 * M11 + M12 * M12;
    float C12 = M10 * M20 + M11 * M21 + M12 * M22;
    float C22 = M20 * M20 + M21 * M21 + M22 * M22;

    // camera transform
    const float* vm = viewmats + c * 16;
    float V00 = vm[0], V01 = vm[1], V02 = vm[2], T0 = vm[3];
    float V10 = vm[4], V11 = vm[5], V12 = vm[6], T1 = vm[7];
    float V20 = vm[8], V21 = vm[9], V22 = vm[10], T2 = vm[11];
    float mex = means[n * 3 + 0], mey = means[n * 3 + 1], mez = means[n * 3 + 2];
    float tx = V00 * mex + V01 * mey + V02 * mez + T0;
    float ty = V10 * mex + V11 * mey + V12 * mez + T1;
    float tz = V20 * mex + V21 * mey + V22 * mez + T2;

    float fx = Ks[c * 9 + 0], fy = Ks[c * 9 + 4], cx = Ks[c * 9 + 2], cy = Ks[c * 9 + 5];
    float tzs = (tz > NEARP) ? tz : NEARP;
    float iz = 1.0f / tzs;
    float m2x = fx * tx * iz + cx;
    float m2y = fy * ty * iz + cy;

    // cov_cam = V cov3d V^T
    float A00 = V00 * C00 + V01 * C01 + V02 * C02;
    float A01 = V00 * C01 + V01 * C11 + V02 * C12;
    float A02 = V00 * C02 + V01 * C12 + V02 * C22;
    float A10 = V10 * C00 + V11 * C01 + V12 * C02;
    float A11 = V10 * C01 + V11 * C11 + V12 * C12;
    float A12 = V10 * C02 + V11 * C12 + V12 * C22;
    float A20 = V20 * C00 + V21 * C01 + V22 * C02;
    float A21 = V20 * C01 + V21 * C11 + V22 * C12;
    float A22 = V20 * C02 + V21 * C12 + V22 * C22;
    float S00 = A00 * V00 + A01 * V01 + A02 * V02;
    float S01 = A00 * V10 + A01 * V11 + A02 * V12;
    float S02 = A00 * V20 + A01 * V21 + A02 * V22;
    float S11 = A10 * V10 + A11 * V11 + A12 * V12;
    float S12 = A10 * V20 + A11 * V21 + A12 * V22;
    float S22 = A20 * V20 + A21 * V21 + A22 * V22;

    // J: 2x3 projection jacobian (uses clamped z)
    float J00 = fx * iz, J02 = -fx * tx * iz * iz;
    float J11 = fy * iz, J12 = -fy * ty * iz * iz;

    float c2_00 = J00 * J00 * S00 + 2.0f * J00 * J02 * S02 + J02 * J02 * S22;
    float c2_01 = J00 * J11 * S01 + J00 * J12 * S02 + J02 * J11 * S12 + J02 * J12 * S22;
    float c2_11 = J11 * J11 * S11 + 2.0f * J11 * J12 * S12 + J12 * J12 * S22;

    float a = c2_00 + BLUR;
    float cc = c2_11 + BLUR;
    float b = c2_01;
    float det = a * cc - b * b;
    bool valid = (tz > NEARP) && (det > 1e-12f);

    float ia, ib, ic, op;
    if (valid) {
        float inv = 1.0f / det;
        ia = cc * inv;
        ib = -b * inv;
        ic = a * inv;
        op = sigmoidf_(opac_logits[n]);
    } else {
        // zero conic AND opacity so alpha == 0 exactly (no 0*inf NaN)
        ia = 0.0f; ib = 0.0f; ic = 0.0f; op = 0.0f;
    }
    float cr = sigmoidf_(color_logits[n * 3 + 0]);
    float cg = sigmoidf_(color_logits[n * 3 + 1]);
    float cb = sigmoidf_(color_logits[n * 3 + 2]);

    size_t base = (size_t)(c * N + n) * 3;
    unsorted[base + 0] = make_float4(m2x, m2y, ia, ib);
    unsorted[base + 1] = make_float4(ic, op, cr, cg);
    unsorted[base + 2] = make_float4(cb, 0.0f, 0.0f, 0.0f);
    tz_out[c * N + n] = tz;
}

// ---------------------------------------------------------------------------
// Stage 2: stable ascending rank-sort by tz (one block per camera, O(N^2) in LDS)
// ---------------------------------------------------------------------------
__global__ void gs_sort(const float4* __restrict__ unsorted,
                        const float* __restrict__ tzin,
                        float4* __restrict__ sorted,
                        int N) {
    __shared__ float stz[MAXN];
    int c = blockIdx.x;
    for (int i = threadIdx.x; i < N; i += blockDim.x) stz[i] = tzin[c * N + i];
    __syncthreads();
    for (int i = threadIdx.x; i < N; i += blockDim.x) {
        float ti = stz[i];
        int rank = 0;
        for (int j = 0; j < N; j++) {
            float tj = stz[j];
            rank += (tj < ti) || (tj == ti && j < i);  // stable
        }
        size_t src = (size_t)(c * N + i) * 3;
        size_t dst = (size_t)(c * N + rank) * 3;
        sorted[dst + 0] = unsorted[src + 0];
        sorted[dst + 1] = unsorted[src + 1];
        sorted[dst + 2] = unsorted[src + 2];
    }
}

// ---------------------------------------------------------------------------
// Stage 3: per-pixel front-to-back compositing; gaussians staged via LDS chunks
// ---------------------------------------------------------------------------
__global__ void __launch_bounds__(256) gs_render(const float4* __restrict__ sorted,
                                                 float* __restrict__ out,
                                                 int N, int W, int H) {
    __shared__ float4 sg[CHUNK * 3];
    int c = blockIdx.z;
    int lx = threadIdx.x % TILE;
    int ly = threadIdx.x / TILE;
    int x = blockIdx.x * TILE + lx;
    int y = blockIdx.y * TILE + ly;
    float px = (float)x + 0.5f;
    float py = (float)y + 0.5f;

    float T = 1.0f, accr = 0.0f, accg = 0.0f, accb = 0.0f;
    const float4* base = sorted + (size_t)c * N * 3;

    for (int start = 0; start < N; start += CHUNK) {
        int cnt = min(CHUNK, N - start);
        __syncthreads();
        for (int t = threadIdx.x; t < cnt * 3; t += blockDim.x) {
            sg[t] = base[(size_t)start * 3 + t];
        }
        __syncthreads();
        if (__any(T > 1e-6f)) {  // wave-uniform skip once fully saturated
            for (int k = 0; k < cnt; k++) {
                float4 f0 = sg[k * 3 + 0];
                float4 f1 = sg[k * 3 + 1];
                float4 f2 = sg[k * 3 + 2];
                float dx = px - f0.x;
                float dy = py - f0.y;
                float quad = f0.z * dx * dx + 2.0f * f0.w * dx * dy + f1.x * dy * dy;
                float alpha = f1.y * __expf(-0.5f * quad);
                alpha = fminf(alpha, MAX_ALPHA);
                float wgt = alpha * T;
                accr += wgt * f1.z;
                accg += wgt * f1.w;
                accb += wgt * f2.x;
                T *= (1.0f - alpha);
            }
        }
    }
    if (x < W && y < H) {
        size_t o = (((size_t)c * H + y) * W + x) * 3;
        out[o + 0] = accr;
        out[o + 1] = accg;
        out[o + 2] = accb;
    }
}

extern "C" void kernel_launch(void* const* d_in, const int* in_sizes, int n_in,
                              void* d_out, int out_size, void* d_ws, size_t ws_size,
                              hipStream_t stream) {
    const float* viewmats = (const float*)d_in[0];
    const float* Ks = (const float*)d_in[1];
    const float* means = (const float*)d_in[2];
    const float* quats = (const float*)d_in[3];
    const float* log_scales = (const float*)d_in[4];
    const float* opac_logits = (const float*)d_in[5];
    const float* color_logits = (const float*)d_in[6];
    float* out = (float*)d_out;

    int N = in_sizes[2] / 3;       // means: (N,3)
    int C = in_sizes[0] / 16;      // viewmats: (C,4,4)
    // out_size = C*H*W*3; setup uses square W==H
    int pix = out_size / (C * 3);
    int W = (int)(sqrt((double)pix) + 0.5);
    int H = pix / W;

    // workspace layout: sorted | unsorted | tz
    float4* sorted = (float4*)d_ws;
    float4* unsorted = sorted + (size_t)C * N * 3;
    float* tzbuf = (float*)(unsorted + (size_t)C * N * 3);

    int total = C * N;
    gs_preprocess<<<(total + 255) / 256, 256, 0, stream>>>(
        viewmats, Ks, means, quats, log_scales, opac_logits, color_logits,
        unsorted, tzbuf, N, C);

    gs_sort<<<C, 256, 0, stream>>>(unsorted, tzbuf, sorted, N);

    dim3 grid((W + TILE - 1) / TILE, (H + TILE - 1) / TILE, C);
    gs_render<<<grid, 256, 0, stream>>>(sorted, out, N, W, H);
}

// Round 3
// 102.114 us; speedup vs baseline: 2.2366x; 2.2366x over previous
//
#include <hip/hip_runtime.h>
#include <math.h>

#define NEARP 0.01f
#define BLUR 0.3f
#define MAX_ALPHA 0.999f
#define TILE 16
#define NSEG 8
#define SEGMAX 256   // max gaussians staged in LDS at once (12 KB)

__device__ __forceinline__ float sigmoidf_(float x) {
    return 1.0f / (1.0f + expf(-x));
}

// ---------------------------------------------------------------------------
// Stage 1: per-(camera,gaussian) preprocess -> 3x float4 struct + tz
// f0=(mean2d.x, mean2d.y, ia, ib)  f1=(ic, opac, r, g)  f2=(b,-,-,-)
// ---------------------------------------------------------------------------
__global__ void gs_preprocess(const float* __restrict__ viewmats,
                              const float* __restrict__ Ks,
                              const float* __restrict__ means,
                              const float* __restrict__ quats,
                              const float* __restrict__ log_scales,
                              const float* __restrict__ opac_logits,
                              const float* __restrict__ color_logits,
                              float4* __restrict__ unsorted,
                              float* __restrict__ tz_out,
                              int N, int C) {
    int idx = blockIdx.x * blockDim.x + threadIdx.x;
    if (idx >= N * C) return;
    int c = idx / N;
    int n = idx - c * N;

    float qw = quats[n * 4 + 0], qx = quats[n * 4 + 1];
    float qy = quats[n * 4 + 2], qz = quats[n * 4 + 3];
    float qn = rsqrtf(qw * qw + qx * qx + qy * qy + qz * qz);
    float w = qw * qn, x = qx * qn, y = qy * qn, z = qz * qn;
    float R00 = 1.0f - 2.0f * (y * y + z * z), R01 = 2.0f * (x * y - w * z), R02 = 2.0f * (x * z + w * y);
    float R10 = 2.0f * (x * y + w * z), R11 = 1.0f - 2.0f * (x * x + z * z), R12 = 2.0f * (y * z - w * x);
    float R20 = 2.0f * (x * z - w * y), R21 = 2.0f * (y * z + w * x), R22 = 1.0f - 2.0f * (x * x + y * y);

    float s0 = expf(log_scales[n * 3 + 0]);
    float s1 = expf(log_scales[n * 3 + 1]);
    float s2 = expf(log_scales[n * 3 + 2]);

    float M00 = R00 * s0, M01 = R01 * s1, M02 = R02 * s2;
    float M10 = R10 * s0, M11 = R11 * s1, M12 = R12 * s2;
    float M20 = R20 * s0, M21 = R21 * s1, M22 = R22 * s2;
    float C00 = M00 * M00 + M01 * M01 + M02 * M02;
    float C01 = M00 * M10 + M01 * M11 + M02 * M12;
    float C02 = M00 * M20 + M01 * M21 + M02 * M22;
    float C11 = M10 * M10 + M11 * M11 + M12 * M12;
    float C12 = M10 * M20 + M11 * M21 + M12 * M22;
    float C22 = M20 * M20 + M21 * M21 + M22 * M22;

    const float* vm = viewmats + c * 16;
    float V00 = vm[0], V01 = vm[1], V02 = vm[2], T0 = vm[3];
    float V10 = vm[4], V11 = vm[5], V12 = vm[6], T1 = vm[7];
    float V20 = vm[8], V21 = vm[9], V22 = vm[10], T2 = vm[11];
    float mex = means[n * 3 + 0], mey = means[n * 3 + 1], mez = means[n * 3 + 2];
    float tx = V00 * mex + V01 * mey + V02 * mez + T0;
    float ty = V10 * mex + V11 * mey + V12 * mez + T1;
    float tz = V20 * mex + V21 * mey + V22 * mez + T2;

    float fx = Ks[c * 9 + 0], fy = Ks[c * 9 + 4], cx = Ks[c * 9 + 2], cy = Ks[c * 9 + 5];
    float tzs = (tz > NEARP) ? tz : NEARP;
    float iz = 1.0f / tzs;
    float m2x = fx * tx * iz + cx;
    float m2y = fy * ty * iz + cy;

    float A00 = V00 * C00 + V01 * C01 + V02 * C02;
    float A01 = V00 * C01 + V01 * C11 + V02 * C12;
    float A02 = V00 * C02 + V01 * C12 + V02 * C22;
    float A10 = V10 * C00 + V11 * C01 + V12 * C02;
    float A11 = V10 * C01 + V11 * C11 + V12 * C12;
    float A12 = V10 * C02 + V11 * C12 + V12 * C22;
    float A20 = V20 * C00 + V21 * C01 + V22 * C02;
    float A21 = V20 * C01 + V21 * C11 + V22 * C12;
    float A22 = V20 * C02 + V21 * C12 + V22 * C22;
    float S00 = A00 * V00 + A01 * V01 + A02 * V02;
    float S01 = A00 * V10 + A01 * V11 + A02 * V12;
    float S02 = A00 * V20 + A01 * V21 + A02 * V22;
    float S11 = A10 * V10 + A11 * V11 + A12 * V12;
    float S12 = A10 * V20 + A11 * V21 + A12 * V22;
    float S22 = A20 * V20 + A21 * V21 + A22 * V22;

    float J00 = fx * iz, J02 = -fx * tx * iz * iz;
    float J11 = fy * iz, J12 = -fy * ty * iz * iz;

    float c2_00 = J00 * J00 * S00 + 2.0f * J00 * J02 * S02 + J02 * J02 * S22;
    float c2_01 = J00 * J11 * S01 + J00 * J12 * S02 + J02 * J11 * S12 + J02 * J12 * S22;
    float c2_11 = J11 * J11 * S11 + 2.0f * J11 * J12 * S12 + J12 * J12 * S22;

    float a = c2_00 + BLUR;
    float cc = c2_11 + BLUR;
    float b = c2_01;
    float det = a * cc - b * b;
    bool valid = (tz > NEARP) && (det > 1e-12f);

    float ia, ib, ic, op;
    if (valid) {
        float inv = 1.0f / det;
        ia = cc * inv;
        ib = -b * inv;
        ic = a * inv;
        op = sigmoidf_(opac_logits[n]);
    } else {
        ia = 0.0f; ib = 0.0f; ic = 0.0f; op = 0.0f;  // alpha==0 exactly, no NaN
    }
    float cr = sigmoidf_(color_logits[n * 3 + 0]);
    float cg = sigmoidf_(color_logits[n * 3 + 1]);
    float cb = sigmoidf_(color_logits[n * 3 + 2]);

    size_t base = (size_t)(c * N + n) * 3;
    unsorted[base + 0] = make_float4(m2x, m2y, ia, ib);
    unsorted[base + 1] = make_float4(ic, op, cr, cg);
    unsorted[base + 2] = make_float4(cb, 0.0f, 0.0f, 0.0f);
    tz_out[c * N + n] = tz;
}

// ---------------------------------------------------------------------------
// Stage 2: wave-per-element stable rank sort. Each wave's 64 lanes partition
// the N comparisons (coalesced L2-hit loads), butterfly-reduce the rank.
// ---------------------------------------------------------------------------
__global__ void gs_sort_wave(const float4* __restrict__ unsorted,
                             const float* __restrict__ tzin,
                             float4* __restrict__ sorted,
                             int N, int C) {
    int gtid = blockIdx.x * blockDim.x + threadIdx.x;
    int wid = gtid >> 6;
    int lane = gtid & 63;
    if (wid >= C * N) return;   // wave-uniform exit
    int c = wid / N;
    int i = wid - c * N;
    const float* tzc = tzin + (size_t)c * N;
    float ti = tzc[i];
    int rank = 0;
    for (int j = lane; j < N; j += 64) {
        float tj = tzc[j];
        rank += (int)((tj < ti) || (tj == ti && j < i));  // stable
    }
#pragma unroll
    for (int off = 1; off < 64; off <<= 1)
        rank += __shfl_xor(rank, off, 64);
    size_t src = (size_t)(c * N + i) * 3;
    size_t dst = (size_t)(c * N + rank) * 3;
    if (lane < 3) sorted[dst + lane] = unsorted[src + lane];
}

// ---------------------------------------------------------------------------
// Stage 3: segmented front-to-back compositing. Blending is associative under
// (acc,T) o (acc',T') = (acc + T*acc', T*T'), so each block composites one
// segment of the sorted list for one 16x16 tile; partials combined in stage 4.
// ---------------------------------------------------------------------------
__global__ void __launch_bounds__(256) gs_render_seg(const float4* __restrict__ sorted,
                                                     float4* __restrict__ partial,
                                                     int N, int W, int H,
                                                     int nseg, int seglen) {
    __shared__ float4 sg[SEGMAX * 3];
    int zc = blockIdx.z;                 // zc = c*nseg + s
    int c = zc / nseg;
    int s = zc - c * nseg;
    int g0 = s * seglen;
    int g1 = min(N, g0 + seglen);

    int lx = threadIdx.x % TILE;
    int ly = threadIdx.x / TILE;
    int x = blockIdx.x * TILE + lx;
    int y = blockIdx.y * TILE + ly;
    float px = (float)x + 0.5f;
    float py = (float)y + 0.5f;

    float T = 1.0f, accr = 0.0f, accg = 0.0f, accb = 0.0f;
    const float4* base = sorted + (size_t)c * N * 3;

    for (int start = g0; start < g1; start += SEGMAX) {
        int cnt = min(SEGMAX, g1 - start);
        __syncthreads();
        for (int t = threadIdx.x; t < cnt * 3; t += blockDim.x)
            sg[t] = base[(size_t)start * 3 + t];
        __syncthreads();
        if (__any(T > 1e-6f)) {
#pragma unroll 4
            for (int k = 0; k < cnt; k++) {
                float4 f0 = sg[k * 3 + 0];   // uniform addr -> LDS broadcast
                float4 f1 = sg[k * 3 + 1];
                float4 f2 = sg[k * 3 + 2];
                float dx = px - f0.x;
                float dy = py - f0.y;
                float quad = f0.z * dx * dx + 2.0f * f0.w * dx * dy + f1.x * dy * dy;
                float alpha = f1.y * __expf(-0.5f * quad);
                alpha = fminf(alpha, MAX_ALPHA);
                float wgt = alpha * T;
                accr += wgt * f1.z;
                accg += wgt * f1.w;
                accb += wgt * f2.x;
                T *= (1.0f - alpha);
            }
        }
    }
    if (x < W && y < H) {
        partial[((size_t)zc * H + y) * W + x] = make_float4(accr, accg, accb, T);
    }
}

// ---------------------------------------------------------------------------
// Stage 4: fold nseg partials per pixel, in segment order.
// ---------------------------------------------------------------------------
__global__ void gs_combine(const float4* __restrict__ partial,
                           float* __restrict__ out,
                           int W, int H, int nseg, int C) {
    int pid = blockIdx.x * blockDim.x + threadIdx.x;
    int PIX = W * H;
    if (pid >= C * PIX) return;
    int c = pid / PIX;
    int p = pid - c * PIX;
    float T = 1.0f, r = 0.0f, g = 0.0f, b = 0.0f;
    for (int s = 0; s < nseg; s++) {
        float4 ps = partial[(size_t)(c * nseg + s) * PIX + p];
        r += T * ps.x;
        g += T * ps.y;
        b += T * ps.z;
        T *= ps.w;
    }
    size_t o = (size_t)pid * 3;
    out[o + 0] = r;
    out[o + 1] = g;
    out[o + 2] = b;
}

extern "C" void kernel_launch(void* const* d_in, const int* in_sizes, int n_in,
                              void* d_out, int out_size, void* d_ws, size_t ws_size,
                              hipStream_t stream) {
    const float* viewmats = (const float*)d_in[0];
    const float* Ks = (const float*)d_in[1];
    const float* means = (const float*)d_in[2];
    const float* quats = (const float*)d_in[3];
    const float* log_scales = (const float*)d_in[4];
    const float* opac_logits = (const float*)d_in[5];
    const float* color_logits = (const float*)d_in[6];
    float* out = (float*)d_out;

    int N = in_sizes[2] / 3;       // means: (N,3)
    int C = in_sizes[0] / 16;      // viewmats: (C,4,4)
    int pix = out_size / (C * 3);
    int W = (int)(sqrt((double)pix) + 0.5);
    int H = pix / W;

    // workspace: sorted | unsorted | tz | partials
    float4* sorted = (float4*)d_ws;
    float4* unsorted = sorted + (size_t)C * N * 3;
    float* tzbuf = (float*)(unsorted + (size_t)C * N * 3);
    float4* partial = (float4*)(tzbuf + (size_t)C * N);
    // align partial to 16B
    partial = (float4*)(((uintptr_t)partial + 15) & ~(uintptr_t)15);

    int total = C * N;
    gs_preprocess<<<(total + 255) / 256, 256, 0, stream>>>(
        viewmats, Ks, means, quats, log_scales, opac_logits, color_logits,
        unsorted, tzbuf, N, C);

    int sort_threads = total * 64;           // one wave per element
    gs_sort_wave<<<(sort_threads + 255) / 256, 256, 0, stream>>>(
        unsorted, tzbuf, sorted, N, C);

    int nseg = NSEG;
    int seglen = (N + nseg - 1) / nseg;
    dim3 grid((W + TILE - 1) / TILE, (H + TILE - 1) / TILE, C * nseg);
    gs_render_seg<<<grid, 256, 0, stream>>>(sorted, partial, N, W, H, nseg, seglen);

    int cp = C * W * H;
    gs_combine<<<(cp + 255) / 256, 256, 0, stream>>>(partial, out, W, H, nseg, C);
}